// Round 14
// baseline (398.903 us; speedup 1.0000x reference)
//
#include <hip/hip_runtime.h>
#include <hip/hip_bf16.h>

// Problem constants
#define BDIM 8
#define TDIM 256
#define UDIM 64
#define HDIM 640
#define VDIM 1024
#define MDIM (BDIM * TDIM * UDIM)   // 131072

#define BK 32
#define NT (HDIM / BK)              // 20 K-tiles
#define NKC (HDIM / 8)              // 80 k-chunks per row
#define GSTRIDE (NKC * 128)         // 10240 ushort per 16-row group

typedef __attribute__((ext_vector_type(8))) short short8;   // 8 bf16 (16B)
typedef __attribute__((ext_vector_type(4))) float f32x4;

__device__ __forceinline__ ushort f2bf(float x) {
    union { float f; unsigned int u; } v; v.f = x;
    unsigned int r = (v.u + 0x7fffu + ((v.u >> 16) & 1u)) >> 16;  // RNE
    return (ushort)r;
}

// ---------------------------------------------------------------------------
// Fragment-tiled layout (verified r10/r11/r12): element (row,k) lives at
//   chunk c = (row>>4)*80 + (k>>3); ushort idx = c*128 + (row&15)*8 + (k&7)
// One 16x32 MFMA fragment (group g, k-tile t) = contiguous 1KB at
// g*GSTRIDE + t*512, read/staged as base + lane*16B (fully coalesced).
// ---------------------------------------------------------------------------

// Prep 1: W (V x H fp32) -> fragment-tiled bf16. 81920 threads = 320 blocks.
__global__ __launch_bounds__(256) void cvt_w_tiled_kernel(
    const float* __restrict__ W, ushort* __restrict__ Wt)
{
    const int c  = blockIdx.x * 256 + threadIdx.x;
    const int lr = c & 15;
    const int q  = c >> 4;
    const int kc = q % NKC;
    const int g  = q / NKC;
    const int v  = g * 16 + lr;
    const float* src = W + (size_t)v * HDIM + kc * 8;
    f32x4 w0 = *(const f32x4*)src;
    f32x4 w1 = *(const f32x4*)(src + 4);
    short8 o;
    #pragma unroll
    for (int e = 0; e < 4; ++e) {
        o[e]     = (short)f2bf(w0[e]);
        o[e + 4] = (short)f2bf(w1[e]);
    }
    *(short8*)(Wt + (size_t)c * 8) = o;
}

// Prep 2: h = relu(f+p), fragment-tiled. 10,485,760 threads = 40960 blocks.
__global__ __launch_bounds__(256) void build_h_tiled_kernel(
    const float* __restrict__ f, const float* __restrict__ p,
    ushort* __restrict__ ht)
{
    const int c  = blockIdx.x * 256 + threadIdx.x;
    const int lr = c & 15;
    const int q  = c >> 4;
    const int kc = q % NKC;
    const int g  = q / NKC;
    const int m  = g * 16 + lr;
    const int b  = m >> 14;
    const int t  = (m >> 6) & (TDIM - 1);
    const int u  = m & (UDIM - 1);
    const int k  = kc * 8;
    const float* fr = f + (size_t)(b * TDIM + t) * HDIM + k;
    const float* pr = p + (size_t)(b * UDIM + u) * HDIM + k;
    f32x4 f0 = *(const f32x4*)fr;
    f32x4 f1 = *(const f32x4*)(fr + 4);
    f32x4 p0 = *(const f32x4*)pr;
    f32x4 p1 = *(const f32x4*)(pr + 4);
    short8 o;
    #pragma unroll
    for (int e = 0; e < 4; ++e) {
        float a0 = fmaxf(f0[e] + p0[e], 0.0f);
        float a1 = fmaxf(f1[e] + p1[e], 0.0f);
        o[e]     = (short)f2bf(a0);
        o[e + 4] = (short)f2bf(a1);
    }
    *(short8*)(ht + (size_t)c * 8) = o;
}

#define GLDS(srcptr, ldsptr)                                                   \
    __builtin_amdgcn_global_load_lds(                                          \
        (const __attribute__((address_space(1))) void*)(srcptr),               \
        (__attribute__((address_space(3))) void*)(ldsptr), 16, 0, 0)

// ========= ring-3 GEMM: r12 geometry x r7 one-barrier x prefetch-2 =========
// Block 256m x 128n, 4 waves (2x2), per-wave 128x64, acc 8x4. BK=32.
// LDS ring: 3 buffers x 24KB = 72KB -> 2 blocks/CU (pipe budgets: TA 46,
// LDS 93 B/cyc, both under ceiling). ONE barrier per tile, prefetch dist 2,
// counted vmcnt(6) (6 staging instr/wave/tile), drains only at tail.
//
// Epoch audit (body: vmcnt; BAR_t; ds_read buf[t%3]; STG(t+2 -> buf[(t+2)%3]);
// MFMA):  reads and writes disjoint mod 3 (2!=0); every wave's tile-t loads
// retired by ITS vmcnt(6) before BAR_t (in-order vmem retire); a wave's
// tile-(t-1) frag reads are consumed (lgkm->MFMA) before it arrives at
// BAR_t, and the fast wave's STG into buf[(t-1)%3] only issues after BAR_t.
// Ledger: at vmcnt, outstanding = {t:6, t+1:6} -> vmcnt(6) retires tile t.
__global__ __launch_bounds__(256, 2) void hgemm_ring_kernel(
    const ushort* __restrict__ ht,    // fragment-tiled h
    const ushort* __restrict__ Wt,    // fragment-tiled W
    const float* __restrict__ bias,   // (V)
    float* __restrict__ out)          // (M,V) fp32
{
    __shared__ ushort Sh[3][12288];   // [ring][16 A-runs | 8 B-runs] 24KB each

    const int tid  = threadIdx.x;
    const int lane = tid & 63;
    const int wave = tid >> 6;   // 0..3
    const int wm   = wave >> 1;  // 0..1 -> 128-row half
    const int wn   = wave & 1;   // 0..1 -> 64-col half

    // Bijective XCD swizzle: 4096 blocks (%8==0). XCD x runs works
    // [x*512,(x+1)*512): 8 ntiles of one mtile consecutive -> A panel
    // L2-reused 8x, Wt (1.25MB) L2-resident per XCD.
    const int bid   = blockIdx.x;
    const int work  = (bid & 7) * 512 + (bid >> 3);
    const int mtile = work >> 3;        // 0..511
    const int ntile = work & 7;         // 0..7
    const int m0 = mtile * 256;
    const int v0 = ntile * 128;

    const int gA0 = mtile * 16;         // 16 A groups
    const int gB0 = ntile * 8;          // 8 B groups
    const int la  = lane * 8;           // per-lane 16B within a 1KB run

    // Per-wave staging: runs q = wave*6 + i, i=0..5 (16 A runs + 8 B runs).
    const ushort* sbase[6];
    int doff[6];
    #pragma unroll
    for (int i = 0; i < 6; ++i) {
        const int q = wave * 6 + i;
        if (q < 16) {
            sbase[i] = ht + (size_t)(gA0 + q) * GSTRIDE + la;
            doff[i]  = q * 512;
        } else {
            sbase[i] = Wt + (size_t)(gB0 + (q - 16)) * GSTRIDE + la;
            doff[i]  = 8192 + (q - 16) * 512;
        }
    }

    f32x4 acc[8][4];
    #pragma unroll
    for (int i = 0; i < 8; ++i)
        #pragma unroll
        for (int j = 0; j < 4; ++j)
            acc[i][j] = (f32x4)0.0f;

#define STG(kt, bf) do {                                                       \
        _Pragma("unroll")                                                      \
        for (int i_ = 0; i_ < 6; ++i_)                                         \
            GLDS(sbase[i_] + (kt) * 512, &Sh[bf][doff[i_]]);                   \
    } while (0)

    STG(0, 0);
    STG(1, 1);

    int d = 0;          // buffer holding tile t
    int e = 2;          // buffer receiving tile t+2
    #pragma unroll 1
    for (int t = 0; t < NT; ++t) {
        if (t < NT - 1) { asm volatile("s_waitcnt vmcnt(6)" ::: "memory"); }
        else            { asm volatile("s_waitcnt vmcnt(0)" ::: "memory"); }
        __builtin_amdgcn_sched_barrier(0);
        __builtin_amdgcn_s_barrier();          // tile t landed for all waves
        __builtin_amdgcn_sched_barrier(0);

        short8 afr[8], bfr[4];
        #pragma unroll
        for (int mi = 0; mi < 8; ++mi)
            afr[mi] = *(const short8*)(&Sh[d][(wm * 8 + mi) * 512 + la]);
        #pragma unroll
        for (int ni = 0; ni < 4; ++ni)
            bfr[ni] = *(const short8*)(&Sh[d][8192 + (wn * 4 + ni) * 512 + la]);

        if (t + 2 < NT) STG(t + 2, e);         // into buf[(t+2)%3]

        __builtin_amdgcn_s_setprio(1);
        #pragma unroll
        for (int mi = 0; mi < 8; ++mi)
            #pragma unroll
            for (int ni = 0; ni < 4; ++ni)
                acc[mi][ni] = __builtin_amdgcn_mfma_f32_16x16x32_bf16(
                    afr[mi], bfr[ni], acc[mi][ni], 0, 0, 0);
        __builtin_amdgcn_s_setprio(0);
        __builtin_amdgcn_sched_barrier(0);     // pin body order across iters

        d = (d == 2) ? 0 : d + 1;
        e = (e == 2) ? 0 : e + 1;
    }
#undef STG

    // Epilogue: C/D col = lane&15, row = (lane>>4)*4 + reg
    const int lr = lane & 15;
    #pragma unroll
    for (int ni = 0; ni < 4; ++ni) {
        const int col = v0 + wn * 64 + ni * 16 + lr;
        const float bv = bias[col];
        #pragma unroll
        for (int mi = 0; mi < 8; ++mi) {
            const int rbase = m0 + wm * 128 + mi * 16 + ((lane >> 4) << 2);
            #pragma unroll
            for (int reg = 0; reg < 4; ++reg) {
                out[(size_t)(rbase + reg) * VDIM + col] = acc[mi][ni][reg] + bv;
            }
        }
    }
}

// ---------------- fallback path (round-1 verified, linear layouts) ---------
__global__ void cvt_w_kernel(const float* __restrict__ W, ushort* __restrict__ Wb) {
    int i = (blockIdx.x * 256 + threadIdx.x) * 4;
    f32x4 w = *(const f32x4*)(W + i);
    ushort4 o;
    o.x = f2bf(w[0]); o.y = f2bf(w[1]); o.z = f2bf(w[2]); o.w = f2bf(w[3]);
    *(ushort4*)(Wb + i) = o;
}

template <bool USE_WB>
__global__ __launch_bounds__(256) void joint_gemm_kernel(
    const float* __restrict__ f, const float* __restrict__ p,
    const float* __restrict__ Wf, const ushort* __restrict__ Wb,
    const float* __restrict__ bias, float* __restrict__ out)
{
    __shared__ ushort Alds[128 * 64];
    __shared__ ushort Blds[128 * 64];

    const int tid  = threadIdx.x;
    const int lane = tid & 63;
    const int wave = tid >> 6;
    const int wm   = wave >> 1;
    const int wn   = wave & 1;

    const int bid   = blockIdx.x;
    const int work  = (bid & 7) * 1024 + (bid >> 3);
    const int mtile = work >> 3;
    const int ntile = work & 7;
    const int m0 = mtile * 128;
    const int v0 = ntile * 128;

    const int b  = m0 >> 14;
    const int t0 = (m0 >> 6) & (TDIM - 1);

    const float*  fbase = f + (size_t)(b * TDIM + t0) * HDIM;
    const float*  pbase = p + (size_t)b * UDIM * HDIM;
    const ushort* wbbase = Wb + (size_t)v0 * HDIM;
    const float*  wfbase = Wf + (size_t)v0 * HDIM;

    f32x4 acc[4][4];
    #pragma unroll
    for (int i = 0; i < 4; ++i)
        #pragma unroll
        for (int j = 0; j < 4; ++j)
            acc[i][j] = (f32x4)0.0f;

    for (int kt = 0; kt < HDIM / 64; ++kt) {
        const int k0 = kt * 64;
        __syncthreads();

        if (USE_WB) {
            #pragma unroll
            for (int it = 0; it < 4; ++it) {
                const int c   = it * 256 + tid;
                const int row = c >> 3;
                const int j   = c & 7;
                const ushort* src = wbbase + row * HDIM + k0 + ((j ^ (row & 7)) << 3);
                GLDS(src, &Blds[(it * 256 + wave * 64) * 8]);
            }
        } else {
            #pragma unroll
            for (int it = 0; it < 4; ++it) {
                const int c   = it * 256 + tid;
                const int row = c >> 3;
                const int j   = c & 7;
                const float* wp = wfbase + row * HDIM + k0 + j * 8;
                f32x4 w0 = *(const f32x4*)wp;
                f32x4 w1 = *(const f32x4*)(wp + 4);
                short8 wv;
                #pragma unroll
                for (int e = 0; e < 4; ++e) {
                    wv[e]     = (short)f2bf(w0[e]);
                    wv[e + 4] = (short)f2bf(w1[e]);
                }
                *(short8*)(&Blds[(row * 8 + (j ^ (row & 7))) * 8]) = wv;
            }
        }

        #pragma unroll
        for (int it = 0; it < 4; ++it) {
            const int c   = it * 256 + tid;
            const int row = c >> 3;
            const int j   = c & 7;
            const float* fp_ = fbase + (row >> 6) * HDIM + k0 + j * 8;
            const float* pp_ = pbase + (row & 63) * HDIM + k0 + j * 8;
            f32x4 f0 = *(const f32x4*)fp_;
            f32x4 f1 = *(const f32x4*)(fp_ + 4);
            f32x4 p0 = *(const f32x4*)pp_;
            f32x4 p1 = *(const f32x4*)(pp_ + 4);
            short8 hv;
            #pragma unroll
            for (int e = 0; e < 4; ++e) {
                float a0 = fmaxf(f0[e] + p0[e], 0.0f);
                float a1 = fmaxf(f1[e] + p1[e], 0.0f);
                hv[e]     = (short)f2bf(a0);
                hv[e + 4] = (short)f2bf(a1);
            }
            *(short8*)(&Alds[(row * 8 + (j ^ (row & 7))) * 8]) = hv;
        }

        __syncthreads();

        #pragma unroll
        for (int ks = 0; ks < 2; ++ks) {
            short8 afr[4], bfr[4];
            #pragma unroll
            for (int mi = 0; mi < 4; ++mi) {
                const int r = wm * 64 + mi * 16 + (lane & 15);
                const int j = ks * 4 + (lane >> 4);
                afr[mi] = *(const short8*)(&Alds[(r * 8 + (j ^ (r & 7))) * 8]);
            }
            #pragma unroll
            for (int ni = 0; ni < 4; ++ni) {
                const int r = wn * 64 + ni * 16 + (lane & 15);
                const int j = ks * 4 + (lane >> 4);
                bfr[ni] = *(const short8*)(&Blds[(r * 8 + (j ^ (r & 7))) * 8]);
            }
            #pragma unroll
            for (int mi = 0; mi < 4; ++mi)
                #pragma unroll
                for (int ni = 0; ni < 4; ++ni)
                    acc[mi][ni] = __builtin_amdgcn_mfma_f32_16x16x32_bf16(
                        afr[mi], bfr[ni], acc[mi][ni], 0, 0, 0);
        }
    }

    #pragma unroll
    for (int ni = 0; ni < 4; ++ni) {
        const int col = v0 + wn * 64 + ni * 16 + (lane & 15);
        const float bv = bias[col];
        #pragma unroll
        for (int mi = 0; mi < 4; ++mi) {
            const int rbase = m0 + wm * 64 + mi * 16 + ((lane >> 4) << 2);
            #pragma unroll
            for (int reg = 0; reg < 4; ++reg) {
                out[(size_t)(rbase + reg) * VDIM + col] = acc[mi][ni][reg] + bv;
            }
        }
    }
}

extern "C" void kernel_launch(void* const* d_in, const int* in_sizes, int n_in,
                              void* d_out, int out_size, void* d_ws, size_t ws_size,
                              hipStream_t stream) {
    const float* f    = (const float*)d_in[0];   // (8,256,640)
    const float* p    = (const float*)d_in[1];   // (8,64,640)
    const float* W    = (const float*)d_in[2];   // (1024,640)
    const float* bias = (const float*)d_in[3];   // (1024)
    float* out = (float*)d_out;                  // (8,256,64,1024) fp32

    const size_t wb_bytes = (size_t)VDIM * HDIM * sizeof(ushort);   // 1.25 MB
    const size_t h_bytes  = (size_t)MDIM * HDIM * sizeof(ushort);   // 160 MB

    if (ws_size >= wb_bytes + h_bytes) {
        ushort* Wt = (ushort*)d_ws;
        ushort* ht = (ushort*)((char*)d_ws + wb_bytes);
        cvt_w_tiled_kernel<<<(VDIM * HDIM / 8) / 256, 256, 0, stream>>>(W, Wt);
        build_h_tiled_kernel<<<(MDIM / 256) * (HDIM / 8), 256, 0, stream>>>(f, p, ht);
        const int grid = (MDIM / 256) * (VDIM / 128);   // 4096
        hgemm_ring_kernel<<<grid, 256, 0, stream>>>(ht, Wt, bias, out);
    } else if (ws_size >= wb_bytes) {
        ushort* Wb = (ushort*)d_ws;
        cvt_w_kernel<<<(VDIM * HDIM) / 1024, 256, 0, stream>>>(W, Wb);
        joint_gemm_kernel<true><<<(MDIM / 128) * (VDIM / 128), 256, 0, stream>>>(
            f, p, W, Wb, bias, out);
    } else {
        joint_gemm_kernel<false><<<(MDIM / 128) * (VDIM / 128), 256, 0, stream>>>(
            f, p, W, nullptr, bias, out);
    }
}